// Round 6
// baseline (375.696 us; speedup 1.0000x reference)
//
#include <hip/hip_runtime.h>
#include <hip/hip_fp16.h>

#define N_NODES 500000
#define N_CELLS 1000000
#define N_PTS   8000000

typedef float f32x4 __attribute__((ext_vector_type(4)));
typedef float f32x2 __attribute__((ext_vector_type(2)));

// ---------------- Pass 0: pack nodal (2,N) f32 -> interleaved half2 table (2 MB) ----------------
__global__ __launch_bounds__(256) void pack_nodal_h2_kernel(
    const float* __restrict__ nodal,   // (2, N_NODES)
    __half2*     __restrict__ nodal_h2)// (N_NODES,)
{
    const int n0 = (blockIdx.x * blockDim.x + threadIdx.x) * 4;
    if (n0 >= N_NODES) return;
    const f32x4 a = *reinterpret_cast<const f32x4*>(nodal + n0);
    const f32x4 b = *reinterpret_cast<const f32x4*>(nodal + N_NODES + n0);
    __half2 h[4];
    h[0] = __floats2half2_rn(a.x, b.x);
    h[1] = __floats2half2_rn(a.y, b.y);
    h[2] = __floats2half2_rn(a.z, b.z);
    h[3] = __floats2half2_rn(a.w, b.w);
    *reinterpret_cast<f32x4*>(nodal_h2 + n0) = *reinterpret_cast<f32x4*>(h);
}

// ---------------- Pass 1: gather per-cell nodal values into f16 rows (1 cell/thread) ----------------
// cellvals[c] = 16 halves (32B, aligned): h2[k] = (v0(nk), v1(nk)) for k=0..5, pad = 0
__global__ __launch_bounds__(256) void gather_cellvals_f16_kernel(
    const __half2* __restrict__ nodal_h2, // (N_NODES,) interleaved (v0,v1)
    const int*     __restrict__ conn,     // (N_CELLS, 6), 1-based
    __half*        __restrict__ cellvals) // (N_CELLS, 16) halves
{
    const int c = blockIdx.x * blockDim.x + threadIdx.x;
    if (c >= N_CELLS) return;

    // conn row: 24B at 8B alignment -> 3 x int2
    const int2* cp = reinterpret_cast<const int2*>(conn + (size_t)c * 6);
    const int2 i0 = cp[0], i1 = cp[1], i2 = cp[2];
    const int n[6] = { i0.x, i0.y, i1.x, i1.y, i2.x, i2.y };

    union Row { __half2 h2[8]; f32x4 f4[2]; };
    Row r;
    #pragma unroll
    for (int k = 0; k < 6; ++k) {
        r.h2[k] = nodal_h2[n[k] - 1];  // 4B gather, 2MB L2-resident table
    }
    r.h2[6] = __floats2half2_rn(0.f, 0.f);
    r.h2[7] = __floats2half2_rn(0.f, 0.f);
    f32x4* dst = reinterpret_cast<f32x4*>(cellvals + (size_t)c * 16);
    dst[0] = r.f4[0];
    dst[1] = r.f4[1];
}

// ---------------- Pass 2: per-point interpolation (8 points/thread) ----------------
__global__ __launch_bounds__(256) void interp2d_f16_kernel(
    const __half* __restrict__ cellvals, // (N_CELLS, 16) halves
    const float*  __restrict__ sf,       // (N_PTS, 6)
    const int*    __restrict__ cid,      // (N_PTS,)
    float* __restrict__ out)             // (2, N_PTS)
{
    const int t  = blockIdx.x * blockDim.x + threadIdx.x;
    const int p0 = t * 8;
    if (p0 >= N_PTS) return;

    // 8 cell ids: 2 x int4 (32B aligned)
    const int4* cidp = reinterpret_cast<const int4*>(cid + p0);
    const int4 ca = cidp[0], cb = cidp[1];
    const int cells[8] = { ca.x, ca.y, ca.z, ca.w, cb.x, cb.y, cb.z, cb.w };

    // issue all 8 random row loads up front (16 loads, all independent)
    union RowA { f32x4 f; __half2 h2[4]; };
    union RowB { f32x2 f; __half2 h2[2]; };
    RowA ra[8]; RowB rb[8];
    #pragma unroll
    for (int i = 0; i < 8; ++i) {
        const __half* row = cellvals + (size_t)cells[i] * 16;
        ra[i].f = *reinterpret_cast<const f32x4*>(row);
        rb[i].f = *reinterpret_cast<const f32x2*>(row + 8);
    }

    // 48 shape-function floats: 12 x float4 = exactly 3 private 64B lines (t*192B aligned)
    const float4* sfp = reinterpret_cast<const float4*>(sf + (size_t)p0 * 6);
    float w[48];
    #pragma unroll
    for (int j = 0; j < 12; ++j) {
        const float4 s = sfp[j];
        w[4 * j + 0] = s.x; w[4 * j + 1] = s.y; w[4 * j + 2] = s.z; w[4 * j + 3] = s.w;
    }

    float o0[8], o1[8];
    #pragma unroll
    for (int i = 0; i < 8; ++i) {
        float a0 = 0.f, a1 = 0.f;
        #pragma unroll
        for (int k = 0; k < 6; ++k) {
            const float2 v = __half22float2(k < 4 ? ra[i].h2[k] : rb[i].h2[k - 4]);
            const float wk = w[i * 6 + k];
            a0 = fmaf(wk, v.x, a0);
            a1 = fmaf(wk, v.y, a1);
        }
        o0[i] = a0; o1[i] = a1;
    }

    // NT stores: write-once full lines, keep them out of L2
    f32x4 u0, u1, v0, v1;
    u0.x = o0[0]; u0.y = o0[1]; u0.z = o0[2]; u0.w = o0[3];
    u1.x = o0[4]; u1.y = o0[5]; u1.z = o0[6]; u1.w = o0[7];
    v0.x = o1[0]; v0.y = o1[1]; v0.z = o1[2]; v0.w = o1[3];
    v1.x = o1[4]; v1.y = o1[5]; v1.z = o1[6]; v1.w = o1[7];
    __builtin_nontemporal_store(u0, reinterpret_cast<f32x4*>(out + p0));
    __builtin_nontemporal_store(u1, reinterpret_cast<f32x4*>(out + p0 + 4));
    __builtin_nontemporal_store(v0, reinterpret_cast<f32x4*>(out + N_PTS + p0));
    __builtin_nontemporal_store(v1, reinterpret_cast<f32x4*>(out + N_PTS + p0 + 4));
}

// ---------------- Fallback (round-1 direct kernel) ----------------
__global__ __launch_bounds__(256) void interp2d_direct_kernel(
    const float* __restrict__ nodal,
    const float* __restrict__ sf,
    const int*   __restrict__ conn,
    const int*   __restrict__ cid,
    float* __restrict__ out)
{
    const int t  = blockIdx.x * blockDim.x + threadIdx.x;
    const int p0 = t * 2;
    if (p0 >= N_PTS) return;

    const int2 c = *reinterpret_cast<const int2*>(cid + p0);
    const float4* sfp = reinterpret_cast<const float4*>(sf + (size_t)p0 * 6);
    const float4 s0 = sfp[0];
    const float4 s1 = sfp[1];
    const float4 s2 = sfp[2];
    const float w0[6] = { s0.x, s0.y, s0.z, s0.w, s1.x, s1.y };
    const float w1[6] = { s1.z, s1.w, s2.x, s2.y, s2.z, s2.w };

    float o00 = 0.f, o01 = 0.f, o10 = 0.f, o11 = 0.f;
    {
        const int* cr = conn + (size_t)c.x * 6;
        #pragma unroll
        for (int k = 0; k < 6; ++k) {
            const int node = cr[k] - 1;
            o00 = fmaf(w0[k], nodal[node], o00);
            o01 = fmaf(w0[k], nodal[N_NODES + node], o01);
        }
    }
    {
        const int* cr = conn + (size_t)c.y * 6;
        #pragma unroll
        for (int k = 0; k < 6; ++k) {
            const int node = cr[k] - 1;
            o10 = fmaf(w1[k], nodal[node], o10);
            o11 = fmaf(w1[k], nodal[N_NODES + node], o11);
        }
    }
    *reinterpret_cast<float2*>(out + p0)         = make_float2(o00, o10);
    *reinterpret_cast<float2*>(out + N_PTS + p0) = make_float2(o01, o11);
}

extern "C" void kernel_launch(void* const* d_in, const int* in_sizes, int n_in,
                              void* d_out, int out_size, void* d_ws, size_t ws_size,
                              hipStream_t stream) {
    const float* nodal = (const float*)d_in[0];  // (2, N_NODES)
    const float* sf    = (const float*)d_in[1];  // (N_PTS, 6)
    const int*   conn  = (const int*)d_in[2];    // (N_CELLS, 6)
    const int*   cid   = (const int*)d_in[3];    // (N_PTS,)
    float* out = (float*)d_out;                  // (2, N_PTS)

    const size_t cellvals_bytes = (size_t)N_CELLS * 16 * sizeof(__half);   // 32 MB
    const size_t nodal_h2_bytes = (size_t)N_NODES * sizeof(__half2);       // 2 MB

    if (ws_size >= cellvals_bytes + nodal_h2_bytes) {
        __half*  cellvals = (__half*)d_ws;
        __half2* nodal_h2 = (__half2*)((char*)d_ws + cellvals_bytes);
        {
            const int threads = 256;
            const int blocks = (N_NODES / 4 + threads - 1) / threads;
            pack_nodal_h2_kernel<<<blocks, threads, 0, stream>>>(nodal, nodal_h2);
        }
        {
            const int threads = 256;
            const int blocks = (N_CELLS + threads - 1) / threads;
            gather_cellvals_f16_kernel<<<blocks, threads, 0, stream>>>(nodal_h2, conn, cellvals);
        }
        {
            const int threads = 256;
            const int blocks = (N_PTS / 8 + threads - 1) / threads;
            interp2d_f16_kernel<<<blocks, threads, 0, stream>>>(cellvals, sf, cid, out);
        }
    } else {
        const int threads = 256;
        const int blocks = (N_PTS / 2 + threads - 1) / threads;
        interp2d_direct_kernel<<<blocks, threads, 0, stream>>>(nodal, sf, conn, cid, out);
    }
}

// Round 7
// 275.876 us; speedup vs baseline: 1.3618x; 1.3618x over previous
//
#include <hip/hip_runtime.h>
#include <hip/hip_fp16.h>

#define N_NODES 500000
#define N_CELLS 1000000
#define N_PTS   8000000

typedef float f32x4 __attribute__((ext_vector_type(4)));
typedef float f32x2 __attribute__((ext_vector_type(2)));
typedef int   i32x4 __attribute__((ext_vector_type(4)));
typedef int   i32x2 __attribute__((ext_vector_type(2)));

// ---------------- Pass 0: pack nodal (2,N) f32 -> interleaved half2 table (2 MB) ----------------
__global__ __launch_bounds__(256) void pack_nodal_h2_kernel(
    const float* __restrict__ nodal,   // (2, N_NODES)
    __half2*     __restrict__ nodal_h2)// (N_NODES,)
{
    const int n0 = (blockIdx.x * blockDim.x + threadIdx.x) * 4;
    if (n0 >= N_NODES) return;
    const f32x4 a = *reinterpret_cast<const f32x4*>(nodal + n0);
    const f32x4 b = *reinterpret_cast<const f32x4*>(nodal + N_NODES + n0);
    __half2 h[4];
    h[0] = __floats2half2_rn(a.x, b.x);
    h[1] = __floats2half2_rn(a.y, b.y);
    h[2] = __floats2half2_rn(a.z, b.z);
    h[3] = __floats2half2_rn(a.w, b.w);
    *reinterpret_cast<f32x4*>(nodal_h2 + n0) = *reinterpret_cast<f32x4*>(h);
}

// ---------------- Pass 1: gather per-cell nodal values into f16 rows (1 cell/thread) ----------------
// cellvals[c] = 16 halves (32B, aligned): h2[k] = (v0(nk), v1(nk)) for k=0..5, pad = 0
__global__ __launch_bounds__(256) void gather_cellvals_f16_kernel(
    const __half2* __restrict__ nodal_h2, // (N_NODES,) interleaved (v0,v1)
    const int*     __restrict__ conn,     // (N_CELLS, 6), 1-based
    __half*        __restrict__ cellvals) // (N_CELLS, 16) halves
{
    const int c = blockIdx.x * blockDim.x + threadIdx.x;
    if (c >= N_CELLS) return;

    // conn row: 24B at 8B alignment -> 3 x int2, NT (streamed once; keep nodal_h2 in L2)
    const i32x2* cp = reinterpret_cast<const i32x2*>(conn + (size_t)c * 6);
    const i32x2 i0 = __builtin_nontemporal_load(cp + 0);
    const i32x2 i1 = __builtin_nontemporal_load(cp + 1);
    const i32x2 i2 = __builtin_nontemporal_load(cp + 2);
    const int n[6] = { i0.x, i0.y, i1.x, i1.y, i2.x, i2.y };

    union Row { __half2 h2[8]; f32x4 f4[2]; };
    Row r;
    #pragma unroll
    for (int k = 0; k < 6; ++k) {
        r.h2[k] = nodal_h2[n[k] - 1];  // 4B gather, 2MB L2-resident table
    }
    r.h2[6] = __floats2half2_rn(0.f, 0.f);
    r.h2[7] = __floats2half2_rn(0.f, 0.f);
    f32x4* dst = reinterpret_cast<f32x4*>(cellvals + (size_t)c * 16);
    dst[0] = r.f4[0];   // regular stores: next kernel reads this table
    dst[1] = r.f4[1];
}

// ---------------- Pass 2: per-point interpolation (2 points/thread) ----------------
__global__ __launch_bounds__(256) void interp2d_f16_kernel(
    const __half* __restrict__ cellvals, // (N_CELLS, 16) halves
    const float*  __restrict__ sf,       // (N_PTS, 6)
    const int*    __restrict__ cid,      // (N_PTS,)
    float* __restrict__ out)             // (2, N_PTS)
{
    const int t  = blockIdx.x * blockDim.x + threadIdx.x;
    const int p0 = t * 2;
    if (p0 >= N_PTS) return;

    const int2 c = *reinterpret_cast<const int2*>(cid + p0);

    // issue both random row loads first (NT: lines used once; protect L1 for sf)
    union RowA { f32x4 f; __half2 h2[4]; };
    union RowB { f32x2 f; __half2 h2[2]; };
    RowA ra0, ra1; RowB rb0, rb1;
    {
        const __half* row0 = cellvals + (size_t)c.x * 16;
        const __half* row1 = cellvals + (size_t)c.y * 16;
        ra0.f = __builtin_nontemporal_load(reinterpret_cast<const f32x4*>(row0));
        rb0.f = __builtin_nontemporal_load(reinterpret_cast<const f32x2*>(row0 + 8));
        ra1.f = __builtin_nontemporal_load(reinterpret_cast<const f32x4*>(row1));
        rb1.f = __builtin_nontemporal_load(reinterpret_cast<const f32x2*>(row1 + 8));
    }

    // 12 shape-function floats: 3 x float4 (48B/lane stride — best L1 locality)
    const float4* sfp = reinterpret_cast<const float4*>(sf + (size_t)p0 * 6);
    const float4 s0 = sfp[0];
    const float4 s1 = sfp[1];
    const float4 s2 = sfp[2];
    const float w0[6] = { s0.x, s0.y, s0.z, s0.w, s1.x, s1.y };
    const float w1[6] = { s1.z, s1.w, s2.x, s2.y, s2.z, s2.w };

    float a0 = 0.f, a1 = 0.f, b0 = 0.f, b1 = 0.f;
    #pragma unroll
    for (int k = 0; k < 6; ++k) {
        const float2 v = __half22float2(k < 4 ? ra0.h2[k] : rb0.h2[k - 4]);
        a0 = fmaf(w0[k], v.x, a0);
        a1 = fmaf(w0[k], v.y, a1);
    }
    #pragma unroll
    for (int k = 0; k < 6; ++k) {
        const float2 v = __half22float2(k < 4 ? ra1.h2[k] : rb1.h2[k - 4]);
        b0 = fmaf(w1[k], v.x, b0);
        b1 = fmaf(w1[k], v.y, b1);
    }

    // NT stores: write-once full lines, keep them out of L2
    f32x2 u; u.x = a0; u.y = b0;
    f32x2 v; v.x = a1; v.y = b1;
    __builtin_nontemporal_store(u, reinterpret_cast<f32x2*>(out + p0));
    __builtin_nontemporal_store(v, reinterpret_cast<f32x2*>(out + N_PTS + p0));
}

// ---------------- Fallback (round-1 direct kernel) ----------------
__global__ __launch_bounds__(256) void interp2d_direct_kernel(
    const float* __restrict__ nodal,
    const float* __restrict__ sf,
    const int*   __restrict__ conn,
    const int*   __restrict__ cid,
    float* __restrict__ out)
{
    const int t  = blockIdx.x * blockDim.x + threadIdx.x;
    const int p0 = t * 2;
    if (p0 >= N_PTS) return;

    const int2 c = *reinterpret_cast<const int2*>(cid + p0);
    const float4* sfp = reinterpret_cast<const float4*>(sf + (size_t)p0 * 6);
    const float4 s0 = sfp[0];
    const float4 s1 = sfp[1];
    const float4 s2 = sfp[2];
    const float w0[6] = { s0.x, s0.y, s0.z, s0.w, s1.x, s1.y };
    const float w1[6] = { s1.z, s1.w, s2.x, s2.y, s2.z, s2.w };

    float o00 = 0.f, o01 = 0.f, o10 = 0.f, o11 = 0.f;
    {
        const int* cr = conn + (size_t)c.x * 6;
        #pragma unroll
        for (int k = 0; k < 6; ++k) {
            const int node = cr[k] - 1;
            o00 = fmaf(w0[k], nodal[node], o00);
            o01 = fmaf(w0[k], nodal[N_NODES + node], o01);
        }
    }
    {
        const int* cr = conn + (size_t)c.y * 6;
        #pragma unroll
        for (int k = 0; k < 6; ++k) {
            const int node = cr[k] - 1;
            o10 = fmaf(w1[k], nodal[node], o10);
            o11 = fmaf(w1[k], nodal[N_NODES + node], o11);
        }
    }
    *reinterpret_cast<float2*>(out + p0)         = make_float2(o00, o10);
    *reinterpret_cast<float2*>(out + N_PTS + p0) = make_float2(o01, o11);
}

extern "C" void kernel_launch(void* const* d_in, const int* in_sizes, int n_in,
                              void* d_out, int out_size, void* d_ws, size_t ws_size,
                              hipStream_t stream) {
    const float* nodal = (const float*)d_in[0];  // (2, N_NODES)
    const float* sf    = (const float*)d_in[1];  // (N_PTS, 6)
    const int*   conn  = (const int*)d_in[2];    // (N_CELLS, 6)
    const int*   cid   = (const int*)d_in[3];    // (N_PTS,)
    float* out = (float*)d_out;                  // (2, N_PTS)

    const size_t cellvals_bytes = (size_t)N_CELLS * 16 * sizeof(__half);   // 32 MB
    const size_t nodal_h2_bytes = (size_t)N_NODES * sizeof(__half2);       // 2 MB

    if (ws_size >= cellvals_bytes + nodal_h2_bytes) {
        __half*  cellvals = (__half*)d_ws;
        __half2* nodal_h2 = (__half2*)((char*)d_ws + cellvals_bytes);
        {
            const int threads = 256;
            const int blocks = (N_NODES / 4 + threads - 1) / threads;
            pack_nodal_h2_kernel<<<blocks, threads, 0, stream>>>(nodal, nodal_h2);
        }
        {
            const int threads = 256;
            const int blocks = (N_CELLS + threads - 1) / threads;
            gather_cellvals_f16_kernel<<<blocks, threads, 0, stream>>>(nodal_h2, conn, cellvals);
        }
        {
            const int threads = 256;
            const int blocks = (N_PTS / 2 + threads - 1) / threads;
            interp2d_f16_kernel<<<blocks, threads, 0, stream>>>(cellvals, sf, cid, out);
        }
    } else {
        const int threads = 256;
        const int blocks = (N_PTS / 2 + threads - 1) / threads;
        interp2d_direct_kernel<<<blocks, threads, 0, stream>>>(nodal, sf, conn, cid, out);
    }
}

// Round 8
// 224.334 us; speedup vs baseline: 1.6747x; 1.2298x over previous
//
#include <hip/hip_runtime.h>
#include <hip/hip_fp16.h>

#define N_NODES 500000
#define N_CELLS 1000000
#define N_PTS   8000000

typedef float f32x4 __attribute__((ext_vector_type(4)));

// ---------------- Pass 0: pack nodal (2,N) f32 -> interleaved half2 table (2 MB) ----------------
__global__ __launch_bounds__(256) void pack_nodal_h2_kernel(
    const float* __restrict__ nodal,   // (2, N_NODES)
    __half2*     __restrict__ nodal_h2)// (N_NODES,)
{
    const int n0 = (blockIdx.x * blockDim.x + threadIdx.x) * 4;
    if (n0 >= N_NODES) return;
    const f32x4 a = *reinterpret_cast<const f32x4*>(nodal + n0);
    const f32x4 b = *reinterpret_cast<const f32x4*>(nodal + N_NODES + n0);
    __half2 h[4];
    h[0] = __floats2half2_rn(a.x, b.x);
    h[1] = __floats2half2_rn(a.y, b.y);
    h[2] = __floats2half2_rn(a.z, b.z);
    h[3] = __floats2half2_rn(a.w, b.w);
    *reinterpret_cast<f32x4*>(nodal_h2 + n0) = *reinterpret_cast<f32x4*>(h);
}

// ---------------- Pass 1: gather per-cell nodal values into f32 64B rows ----------------
// cellvals[c] is a 64B row: [v0(n0), v1(n0), v0(n1), v1(n1), ..., v0(n5), v1(n5), pad*4]
__global__ __launch_bounds__(256) void gather_cellvals_kernel(
    const __half2* __restrict__ nodal_h2, // (N_NODES,) interleaved (v0,v1), 2MB L2-resident
    const int*     __restrict__ conn,     // (N_CELLS, 6), 1-based
    float*         __restrict__ cellvals) // (N_CELLS, 16) f32
{
    const int c = blockIdx.x * blockDim.x + threadIdx.x;
    if (c >= N_CELLS) return;

    // conn row: 24B at 8B alignment -> 3 x int2
    const int2* cp = reinterpret_cast<const int2*>(conn + (size_t)c * 6);
    const int2 i0 = cp[0], i1 = cp[1], i2 = cp[2];
    const int n[6] = { i0.x, i0.y, i1.x, i1.y, i2.x, i2.y };

    float2 v[6];
    #pragma unroll
    for (int k = 0; k < 6; ++k) {
        v[k] = __half22float2(nodal_h2[n[k] - 1]);  // 4B gather from 2MB table
    }

    float4* dst = reinterpret_cast<float4*>(cellvals + (size_t)c * 16);
    dst[0] = make_float4(v[0].x, v[0].y, v[1].x, v[1].y);
    dst[1] = make_float4(v[2].x, v[2].y, v[3].x, v[3].y);
    dst[2] = make_float4(v[4].x, v[4].y, v[5].x, v[5].y);
    dst[3] = make_float4(0.f, 0.f, 0.f, 0.f);   // full 64B line write (no RMW)
}

// ---------------- Pass 2: per-point interpolation (2 points/thread, r2 verbatim) ----------------
__global__ __launch_bounds__(256) void interp2d_cellvals_kernel(
    const float* __restrict__ cellvals, // (N_CELLS, 16)
    const float* __restrict__ sf,       // (N_PTS, 6)
    const int*   __restrict__ cid,      // (N_PTS,)
    float* __restrict__ out)            // (2, N_PTS)
{
    const int t  = blockIdx.x * blockDim.x + threadIdx.x;
    const int p0 = t * 2;
    if (p0 >= N_PTS) return;

    const int2 c = *reinterpret_cast<const int2*>(cid + p0);

    // 12 shape-function floats for points p0, p0+1 (16B aligned: 48B stride)
    const float4* sfp = reinterpret_cast<const float4*>(sf + (size_t)p0 * 6);
    const float4 s0 = sfp[0];
    const float4 s1 = sfp[1];
    const float4 s2 = sfp[2];

    // issue both cell rows up front (each = one 64B line)
    const float4* r0 = reinterpret_cast<const float4*>(cellvals + (size_t)c.x * 16);
    const float4* r1 = reinterpret_cast<const float4*>(cellvals + (size_t)c.y * 16);
    const float4 q00 = r0[0], q01 = r0[1], q02 = r0[2];
    const float4 q10 = r1[0], q11 = r1[1], q12 = r1[2];

    // point 0 weights: s0.x..s1.y ; point 1 weights: s1.z..s2.w
    float a0, a1, b0, b1;
    a0 = s0.x * q00.x; a1 = s0.x * q00.y;
    a0 = fmaf(s0.y, q00.z, a0); a1 = fmaf(s0.y, q00.w, a1);
    a0 = fmaf(s0.z, q01.x, a0); a1 = fmaf(s0.z, q01.y, a1);
    a0 = fmaf(s0.w, q01.z, a0); a1 = fmaf(s0.w, q01.w, a1);
    a0 = fmaf(s1.x, q02.x, a0); a1 = fmaf(s1.x, q02.y, a1);
    a0 = fmaf(s1.y, q02.z, a0); a1 = fmaf(s1.y, q02.w, a1);

    b0 = s1.z * q10.x; b1 = s1.z * q10.y;
    b0 = fmaf(s1.w, q10.z, b0); b1 = fmaf(s1.w, q10.w, b1);
    b0 = fmaf(s2.x, q11.x, b0); b1 = fmaf(s2.x, q11.y, b1);
    b0 = fmaf(s2.y, q11.z, b0); b1 = fmaf(s2.y, q11.w, b1);
    b0 = fmaf(s2.z, q12.x, b0); b1 = fmaf(s2.z, q12.y, b1);
    b0 = fmaf(s2.w, q12.z, b0); b1 = fmaf(s2.w, q12.w, b1);

    *reinterpret_cast<float2*>(out + p0)         = make_float2(a0, b0);
    *reinterpret_cast<float2*>(out + N_PTS + p0) = make_float2(a1, b1);
}

// ---------------- Fallback (round-1 direct kernel) ----------------
__global__ __launch_bounds__(256) void interp2d_direct_kernel(
    const float* __restrict__ nodal,
    const float* __restrict__ sf,
    const int*   __restrict__ conn,
    const int*   __restrict__ cid,
    float* __restrict__ out)
{
    const int t  = blockIdx.x * blockDim.x + threadIdx.x;
    const int p0 = t * 2;
    if (p0 >= N_PTS) return;

    const int2 c = *reinterpret_cast<const int2*>(cid + p0);
    const float4* sfp = reinterpret_cast<const float4*>(sf + (size_t)p0 * 6);
    const float4 s0 = sfp[0];
    const float4 s1 = sfp[1];
    const float4 s2 = sfp[2];
    const float w0[6] = { s0.x, s0.y, s0.z, s0.w, s1.x, s1.y };
    const float w1[6] = { s1.z, s1.w, s2.x, s2.y, s2.z, s2.w };

    float o00 = 0.f, o01 = 0.f, o10 = 0.f, o11 = 0.f;
    {
        const int* cr = conn + (size_t)c.x * 6;
        #pragma unroll
        for (int k = 0; k < 6; ++k) {
            const int node = cr[k] - 1;
            o00 = fmaf(w0[k], nodal[node], o00);
            o01 = fmaf(w0[k], nodal[N_NODES + node], o01);
        }
    }
    {
        const int* cr = conn + (size_t)c.y * 6;
        #pragma unroll
        for (int k = 0; k < 6; ++k) {
            const int node = cr[k] - 1;
            o10 = fmaf(w1[k], nodal[node], o10);
            o11 = fmaf(w1[k], nodal[N_NODES + node], o11);
        }
    }
    *reinterpret_cast<float2*>(out + p0)         = make_float2(o00, o10);
    *reinterpret_cast<float2*>(out + N_PTS + p0) = make_float2(o01, o11);
}

extern "C" void kernel_launch(void* const* d_in, const int* in_sizes, int n_in,
                              void* d_out, int out_size, void* d_ws, size_t ws_size,
                              hipStream_t stream) {
    const float* nodal = (const float*)d_in[0];  // (2, N_NODES)
    const float* sf    = (const float*)d_in[1];  // (N_PTS, 6)
    const int*   conn  = (const int*)d_in[2];    // (N_CELLS, 6)
    const int*   cid   = (const int*)d_in[3];    // (N_PTS,)
    float* out = (float*)d_out;                  // (2, N_PTS)

    const size_t cellvals_bytes = (size_t)N_CELLS * 16 * sizeof(float);  // 64 MB
    const size_t nodal_h2_bytes = (size_t)N_NODES * sizeof(__half2);     // 2 MB

    if (ws_size >= cellvals_bytes + nodal_h2_bytes) {
        float*   cellvals = (float*)d_ws;
        __half2* nodal_h2 = (__half2*)((char*)d_ws + cellvals_bytes);
        {
            const int threads = 256;
            const int blocks = (N_NODES / 4 + threads - 1) / threads;
            pack_nodal_h2_kernel<<<blocks, threads, 0, stream>>>(nodal, nodal_h2);
        }
        {
            const int threads = 256;
            const int blocks = (N_CELLS + threads - 1) / threads;
            gather_cellvals_kernel<<<blocks, threads, 0, stream>>>(nodal_h2, conn, cellvals);
        }
        {
            const int threads = 256;
            const int blocks = (N_PTS / 2 + threads - 1) / threads;
            interp2d_cellvals_kernel<<<blocks, threads, 0, stream>>>(cellvals, sf, cid, out);
        }
    } else {
        const int threads = 256;
        const int blocks = (N_PTS / 2 + threads - 1) / threads;
        interp2d_direct_kernel<<<blocks, threads, 0, stream>>>(nodal, sf, conn, cid, out);
    }
}